// Round 3
// baseline (379.045 us; speedup 1.0000x reference)
//
#include <hip/hip_runtime.h>
#include <hip/hip_bf16.h>

#define NC 30
#define WIDTH 64
#define DD 32
#define BATCH_N 1048576

// ---------------- Stage 1: hypernetwork rows (Wt, Ut, Bt) ----------------
// grid 16 x 128 threads: each thread computes one row j of Wt and Ut (2048 each).
__global__ void hyper_rows(
    const float* __restrict__ t,
    const float* __restrict__ Wc, const float* __restrict__ Wls,
    const float* __restrict__ Ww, const float* __restrict__ Wb,
    const float* __restrict__ Uc, const float* __restrict__ Uls,
    const float* __restrict__ Uw, const float* __restrict__ Ub,
    const float* __restrict__ Bc, const float* __restrict__ Bls,
    const float* __restrict__ Bw, const float* __restrict__ Bb,
    float* __restrict__ outWt, float* __restrict__ outUt, float* __restrict__ outBt)
{
    __shared__ float phiW[NC], phiU[NC], phiB[NC];
    const float tv = t[0];
    const int tid = threadIdx.x;
    if (tid < NC) {
        float dW = fabsf(tv - Wc[tid]) * __expf(-Wls[tid]);
        phiW[tid] = __expf(-dW * dW);
        float dU = fabsf(tv - Uc[tid]) * __expf(-Uls[tid]);
        phiU[tid] = __expf(-dU * dU);
        float dB = fabsf(tv - Bc[tid]) * __expf(-Bls[tid]);
        phiB[tid] = __expf(-dB * dB);
    }
    __syncthreads();
    const int j = blockIdx.x * blockDim.x + tid;   // 0..2047
    float aw = Wb[j];
    float au = Ub[j];
    #pragma unroll
    for (int k = 0; k < NC; ++k) {
        aw += phiW[k] * Ww[j * NC + k];
        au += phiU[k] * Uw[j * NC + k];
    }
    outWt[j] = aw;
    outUt[j] = au;
    if (blockIdx.x == 0 && tid < WIDTH) {
        float ab = Bb[tid];
        #pragma unroll
        for (int k = 0; k < NC; ++k) ab += phiB[k] * Bw[tid * NC + k];
        outBt[tid] = ab;
    }
}

// ---------------- Stage 2: wu[w] = sum_i Wt[w,i]*Ut[w,i] ----------------
__global__ void hyper_wu(const float* __restrict__ Wt, const float* __restrict__ Ut,
                         float* __restrict__ wu)
{
    const int w = threadIdx.x;   // 64 threads
    float s = 0.f;
    #pragma unroll
    for (int i = 0; i < DD; ++i) s += Wt[w * DD + i] * Ut[w * DD + i];
    wu[w] = s;
}

// ---------------- Stage 3: main batched kernel, one thread per element ----------------
// Weights read with wave-uniform indices -> scalar loads (SGPR operands to v_fmac).
__global__ __launch_bounds__(256, 4) void cnf_main(
    const float* __restrict__ z,
    const float* __restrict__ Wt, const float* __restrict__ Ut,
    const float* __restrict__ Bt, const float* __restrict__ wu,
    float* __restrict__ dz, float* __restrict__ dlogp)
{
    const int b = blockIdx.x * 256 + threadIdx.x;

    // load z row: 32 fp32 = 128 B as 8x float4
    float zr[DD];
    {
        const float4* zp = reinterpret_cast<const float4*>(z + (size_t)b * DD);
        #pragma unroll
        for (int q = 0; q < 8; ++q) {
            float4 v = zp[q];
            zr[4 * q + 0] = v.x;
            zr[4 * q + 1] = v.y;
            zr[4 * q + 2] = v.z;
            zr[4 * q + 3] = v.w;
        }
    }

    float acc[DD];
    #pragma unroll
    for (int i = 0; i < DD; ++i) acc[i] = 0.f;
    float tr = 0.f;

    for (int w = 0; w < WIDTH; ++w) {
        const float* wr = Wt + w * DD;   // uniform address -> s_load
        const float* ur = Ut + w * DD;
        float p0 = Bt[w], p1 = 0.f, p2 = 0.f, p3 = 0.f;
        #pragma unroll
        for (int i = 0; i < DD; i += 4) {
            p0 += zr[i + 0] * wr[i + 0];
            p1 += zr[i + 1] * wr[i + 1];
            p2 += zr[i + 2] * wr[i + 2];
            p3 += zr[i + 3] * wr[i + 3];
        }
        const float s = (p0 + p1) + (p2 + p3);
        // tanh(s) = 1 - 2/(e^{2s}+1); exact limits at +/-inf
        const float e = __expf(2.0f * s);
        const float h = 1.0f - 2.0f * __builtin_amdgcn_rcpf(e + 1.0f);
        tr += (1.0f - h * h) * wu[w];
        #pragma unroll
        for (int i = 0; i < DD; ++i) acc[i] += h * ur[i];
    }

    const float inv = 1.0f / (float)WIDTH;
    float4* op = reinterpret_cast<float4*>(dz + (size_t)b * DD);
    #pragma unroll
    for (int q = 0; q < 8; ++q)
        op[q] = make_float4(acc[4 * q + 0] * inv, acc[4 * q + 1] * inv,
                            acc[4 * q + 2] * inv, acc[4 * q + 3] * inv);

    dlogp[b] = -tr * inv;
}

extern "C" void kernel_launch(void* const* d_in, const int* in_sizes, int n_in,
                              void* d_out, int out_size, void* d_ws, size_t ws_size,
                              hipStream_t stream)
{
    const float* t   = (const float*)d_in[0];
    const float* z   = (const float*)d_in[1];
    // d_in[2] = logp_z: unused by the reference outputs
    const float* Wc  = (const float*)d_in[3];
    const float* Wls = (const float*)d_in[4];
    const float* Ww  = (const float*)d_in[5];
    const float* Wb  = (const float*)d_in[6];
    const float* Uc  = (const float*)d_in[7];
    const float* Uls = (const float*)d_in[8];
    const float* Uw  = (const float*)d_in[9];
    const float* Ub  = (const float*)d_in[10];
    const float* Bc  = (const float*)d_in[11];
    const float* Bls = (const float*)d_in[12];
    const float* Bw  = (const float*)d_in[13];
    const float* Bb  = (const float*)d_in[14];

    float* wsWt = (float*)d_ws;          // 2048
    float* wsUt = wsWt + 2048;           // 2048
    float* wsBt = wsUt + 2048;           // 64
    float* wswu = wsBt + 64;             // 64   (total 16.9 KB of d_ws)

    hyper_rows<<<16, 128, 0, stream>>>(t, Wc, Wls, Ww, Wb, Uc, Uls, Uw, Ub,
                                       Bc, Bls, Bw, Bb, wsWt, wsUt, wsBt);
    hyper_wu<<<1, 64, 0, stream>>>(wsWt, wsUt, wswu);

    float* dz = (float*)d_out;
    float* dlogp = dz + (size_t)BATCH_N * DD;
    cnf_main<<<BATCH_N / 256, 256, 0, stream>>>(z, wsWt, wsUt, wsBt, wswu, dz, dlogp);
}

// Round 4
// 283.322 us; speedup vs baseline: 1.3379x; 1.3379x over previous
//
#include <hip/hip_runtime.h>
#include <hip/hip_bf16.h>

#define NC 30
#define WIDTH 64
#define DD 32
#define BATCH_N 1048576

typedef __bf16 bf16x8 __attribute__((ext_vector_type(8)));
typedef float f32x4 __attribute__((ext_vector_type(4)));

__device__ __forceinline__ bf16x8 pack_bf8(float4 a, float4 b) {
    bf16x8 r;
    r[0] = (__bf16)a.x; r[1] = (__bf16)a.y; r[2] = (__bf16)a.z; r[3] = (__bf16)a.w;
    r[4] = (__bf16)b.x; r[5] = (__bf16)b.y; r[6] = (__bf16)b.z; r[7] = (__bf16)b.w;
    return r;
}

// ---------------- Stage 1: hypernetwork (Wt, UtT, Bt, wu) ----------------
// grid 16 x 128: thread j computes Wt[j] and Ut[j]; wu via intra-wave shuffle.
__global__ void hyper_rows(
    const float* __restrict__ t,
    const float* __restrict__ Wc, const float* __restrict__ Wls,
    const float* __restrict__ Ww, const float* __restrict__ Wb,
    const float* __restrict__ Uc, const float* __restrict__ Uls,
    const float* __restrict__ Uw, const float* __restrict__ Ub,
    const float* __restrict__ Bc, const float* __restrict__ Bls,
    const float* __restrict__ Bw, const float* __restrict__ Bb,
    float* __restrict__ outWt, float* __restrict__ outUtT,
    float* __restrict__ outBt, float* __restrict__ outwu)
{
    __shared__ float phiW[NC], phiU[NC], phiB[NC];
    const float tv = t[0];
    const int tid = threadIdx.x;
    if (tid < NC) {
        float dW = fabsf(tv - Wc[tid]) * __expf(-Wls[tid]);
        phiW[tid] = __expf(-dW * dW);
        float dU = fabsf(tv - Uc[tid]) * __expf(-Uls[tid]);
        phiU[tid] = __expf(-dU * dU);
        float dB = fabsf(tv - Bc[tid]) * __expf(-Bls[tid]);
        phiB[tid] = __expf(-dB * dB);
    }
    __syncthreads();
    const int j = blockIdx.x * blockDim.x + tid;   // 0..2047
    float aw = Wb[j];
    float au = Ub[j];
    #pragma unroll
    for (int k = 0; k < NC; ++k) {
        aw += phiW[k] * Ww[j * NC + k];
        au += phiU[k] * Uw[j * NC + k];
    }
    outWt[j] = aw;                       // Wt row-major (64 x 32)
    const int w = j >> 5, i = j & 31;
    outUtT[i * WIDTH + w] = au;          // Ut transposed (32 x 64)

    // wu[w] = sum_i Wt[w,i]*Ut[w,i]: reduce over 32-thread groups
    float p = aw * au;
    #pragma unroll
    for (int off = 1; off < 32; off <<= 1) p += __shfl_xor(p, off, 64);
    if ((tid & 31) == 0) outwu[w] = p;

    if (blockIdx.x == 0 && tid < WIDTH) {
        float ab = Bb[tid];
        #pragma unroll
        for (int k = 0; k < NC; ++k) ab += phiB[k] * Bw[tid * NC + k];
        outBt[tid] = ab;
    }
}

// ---------------- Stage 2: MFMA main kernel ----------------
// Per wave: 8 iterations of a 16-row batch tile.
//   S(16x64) = z(16x32) @ Wt^T          -> 4x mfma 16x16x32 bf16
//   h = tanh(S + Bt); trace partials
//   h -> LDS (C-layout -> A-layout re-tile), bf16, row stride 72 (16B aligned)
//   dz(16x32) = h(16x64) @ Ut           -> 4x mfma (2 n-tiles x 2 k-chunks)
__global__ __launch_bounds__(256, 4) void cnf_main(
    const float* __restrict__ z,
    const float* __restrict__ Wt,   // 64 x 32
    const float* __restrict__ UtT,  // 32 x 64
    const float* __restrict__ Bt, const float* __restrict__ wu,
    float* __restrict__ dz, float* __restrict__ dlogp)
{
    __shared__ __bf16 hbuf[4][16][72];
    const int tid  = threadIdx.x;
    const int wave = tid >> 6;
    const int lane = tid & 63;
    const int l15  = lane & 15;
    const int quad = lane >> 4;          // 0..3
    __bf16 (*hl)[72] = hbuf[wave];

    // ---- preload weight fragments (wave-invariant across the loop) ----
    bf16x8 bW[4];                        // B-frag of Wt^T, n-tile t4: B[k][n]=Wt[n][k]
    #pragma unroll
    for (int t4 = 0; t4 < 4; ++t4) {
        const float4* p = (const float4*)(Wt + (t4 * 16 + l15) * DD + quad * 8);
        bW[t4] = pack_bf8(p[0], p[1]);
    }
    bf16x8 bU[2][2];                     // [k-chunk c][n-tile t2]: B[k2][i]=UtT[i][k2]
    #pragma unroll
    for (int c = 0; c < 2; ++c)
        #pragma unroll
        for (int t2 = 0; t2 < 2; ++t2) {
            const float4* p = (const float4*)(UtT + (t2 * 16 + l15) * WIDTH + c * 32 + quad * 8);
            bU[c][t2] = pack_bf8(p[0], p[1]);
        }
    float bt_l[4], wu_l[4];
    #pragma unroll
    for (int t4 = 0; t4 < 4; ++t4) {
        bt_l[t4] = Bt[t4 * 16 + l15];
        wu_l[t4] = wu[t4 * 16 + l15];
    }

    const size_t gw = (size_t)blockIdx.x * 4 + wave;     // 0..8191, 128 rows each
    const float* zp = z + (gw * 128 + l15) * DD + quad * 8;

    float4 za = ((const float4*)zp)[0];
    float4 zb = ((const float4*)zp)[1];
    const f32x4 zero = {0.f, 0.f, 0.f, 0.f};
    const float inv = 1.0f / (float)WIDTH;

    for (int it = 0; it < 8; ++it) {
        float4 na = {0,0,0,0}, nb = {0,0,0,0};
        if (it < 7) {                                    // wave-uniform branch
            const float4* np = (const float4*)(zp + 16 * DD);
            na = np[0]; nb = np[1];
        }

        // ---- GEMM 1: S = z @ Wt^T ----
        bf16x8 aZ = pack_bf8(za, zb);                    // A[m=l15][k=quad*8+j]
        f32x4 accS[4];
        #pragma unroll
        for (int t4 = 0; t4 < 4; ++t4)
            accS[t4] = __builtin_amdgcn_mfma_f32_16x16x32_bf16(aZ, bW[t4], zero, 0, 0, 0);

        // ---- epilogue: bias + tanh + trace partials + h -> LDS ----
        float part[4] = {0.f, 0.f, 0.f, 0.f};
        #pragma unroll
        for (int t4 = 0; t4 < 4; ++t4) {
            #pragma unroll
            for (int r = 0; r < 4; ++r) {
                const float s = accS[t4][r] + bt_l[t4];
                const float e = __expf(2.0f * s);
                const float h = 1.0f - 2.0f * __builtin_amdgcn_rcpf(e + 1.0f);
                part[r] += (1.0f - h * h) * wu_l[t4];
                hl[quad * 4 + r][t4 * 16 + l15] = (__bf16)h;   // C-layout scatter
            }
        }

        // ---- GEMM 2: dz = h @ Ut ----  (A-frag gather from LDS)
        bf16x8 aH0 = *(const bf16x8*)&hl[l15][quad * 8];        // k2 = quad*8+j
        bf16x8 aH1 = *(const bf16x8*)&hl[l15][32 + quad * 8];   // k2 = 32+quad*8+j
        f32x4 accD[2];
        #pragma unroll
        for (int t2 = 0; t2 < 2; ++t2) {
            f32x4 c0 = __builtin_amdgcn_mfma_f32_16x16x32_bf16(aH0, bU[0][t2], zero, 0, 0, 0);
            accD[t2]  = __builtin_amdgcn_mfma_f32_16x16x32_bf16(aH1, bU[1][t2], c0, 0, 0, 0);
        }

        // ---- trace: reduce part[r] across the 16-lane column group ----
        #pragma unroll
        for (int off = 1; off < 16; off <<= 1)
            #pragma unroll
            for (int r = 0; r < 4; ++r) part[r] += __shfl_xor(part[r], off, 64);

        const size_t row0 = gw * 128 + (size_t)it * 16 + quad * 4;
        if (l15 == 0) {
            #pragma unroll
            for (int r = 0; r < 4; ++r) dlogp[row0 + r] = -part[r] * inv;
        }

        // ---- dz stores (C-layout, 64B-coalesced per 16-lane group) ----
        #pragma unroll
        for (int t2 = 0; t2 < 2; ++t2)
            #pragma unroll
            for (int r = 0; r < 4; ++r)
                dz[(row0 + r) * DD + t2 * 16 + l15] = accD[t2][r] * inv;

        za = na; zb = nb;
        zp += 16 * DD;
    }
}

extern "C" void kernel_launch(void* const* d_in, const int* in_sizes, int n_in,
                              void* d_out, int out_size, void* d_ws, size_t ws_size,
                              hipStream_t stream)
{
    const float* t   = (const float*)d_in[0];
    const float* z   = (const float*)d_in[1];
    // d_in[2] = logp_z: unused by the reference outputs
    const float* Wc  = (const float*)d_in[3];
    const float* Wls = (const float*)d_in[4];
    const float* Ww  = (const float*)d_in[5];
    const float* Wb  = (const float*)d_in[6];
    const float* Uc  = (const float*)d_in[7];
    const float* Uls = (const float*)d_in[8];
    const float* Uw  = (const float*)d_in[9];
    const float* Ub  = (const float*)d_in[10];
    const float* Bc  = (const float*)d_in[11];
    const float* Bls = (const float*)d_in[12];
    const float* Bw  = (const float*)d_in[13];
    const float* Bb  = (const float*)d_in[14];

    float* wsWt  = (float*)d_ws;         // 2048  (Wt 64x32 row-major)
    float* wsUtT = wsWt + 2048;          // 2048  (Ut^T 32x64)
    float* wsBt  = wsUtT + 2048;         // 64
    float* wswu  = wsBt + 64;            // 64

    hyper_rows<<<16, 128, 0, stream>>>(t, Wc, Wls, Ww, Wb, Uc, Uls, Uw, Ub,
                                       Bc, Bls, Bw, Bb, wsWt, wsUtT, wsBt, wswu);

    float* dz = (float*)d_out;
    float* dlogp = dz + (size_t)BATCH_N * DD;
    cnf_main<<<2048, 256, 0, stream>>>(z, wsWt, wsUtT, wsBt, wswu, dz, dlogp);
}